// Round 23
// baseline (444.481 us; speedup 1.0000x reference)
//
#include <hip/hip_runtime.h>
#include <hip/hip_bf16.h>
#include <math.h>

#define BB 4
#define CC 512
#define NHEAD 8
#define HDIM 64
#define NCLS 128
#define DD 768
#define LL 9216
#define BLPIX 36864
#define EPSV 1e-5f
#define GMBLK 144
#define AUXBLK 144
#define LSPLIT 8
#define NLT 72
#define TP 132   // epilogue transpose-tile pitch (shorts)

typedef __hip_bfloat16 bf16;
typedef __attribute__((ext_vector_type(8))) short short8v;
typedef __attribute__((ext_vector_type(4))) short short4v;
typedef __attribute__((ext_vector_type(4))) float f32x4;

__device__ __forceinline__ float bf2f(bf16 v){ return __bfloat162float(v); }
__device__ __forceinline__ bf16 f2bf(float v){ return __float2bfloat16(v); }
__device__ __forceinline__ short bfbits(float v){ bf16 b = __float2bfloat16(v); return *reinterpret_cast<short*>(&b); }
__device__ __forceinline__ float s2f(short s){ bf16 b = *reinterpret_cast<bf16*>(&s); return __bfloat162float(b); }

// ================= wclsg: wcast | clsg =================
__global__ __launch_bounds__(256) void wclsg_k(
    const float* __restrict__ wqkv, const float* __restrict__ wo,
    const float* __restrict__ w1, const float* __restrict__ w2,
    bf16* __restrict__ oq, bf16* __restrict__ oo,
    bf16* __restrict__ o1, bf16* __restrict__ o2,
    const float* __restrict__ cls_embs, const float* __restrict__ gamma_g,
    const float* __restrict__ beta_g, const float* __restrict__ Wg,
    float* __restrict__ g, bf16* __restrict__ gnb)
{
  __shared__ __align__(16) float cn[DD];
  __shared__ float red[256];
  __shared__ float gsh[CC];
  __shared__ float nrm[NHEAD];
  int bid = blockIdx.x;
  int tid = threadIdx.x;
  if (bid < 1536){
    int i = bid * 256 + tid;
    int e = i * 4;
    const float* src; bf16* dst; int off;
    if (e < 786432){ src = wqkv; dst = oq; off = e; }
    else if (e < 1048576){ src = wo; dst = oo; off = e - 786432; }
    else if (e < 1310720){ src = w1; dst = o1; off = e - 1048576; }
    else { src = w2; dst = o2; off = e - 1310720; }
    float4 v = *reinterpret_cast<const float4*>(src + off);
    short4v pk;
    pk[0] = bfbits(v.x); pk[1] = bfbits(v.y); pk[2] = bfbits(v.z); pk[3] = bfbits(v.w);
    *(short4v*)&dst[off] = pk;
    return;
  }
  {
    int n = bid - 1536;
    const float* e = cls_embs + (size_t)n * DD;
    float s = 0.f, ss = 0.f;
    for (int i = tid; i < DD; i += 256){ float v = e[i]; s += v; ss += v * v; }
    red[tid] = s; __syncthreads();
    for (int st = 128; st > 0; st >>= 1){ if (tid < st) red[tid] += red[tid + st]; __syncthreads(); }
    float mean = red[0] / DD; __syncthreads();
    red[tid] = ss; __syncthreads();
    for (int st = 128; st > 0; st >>= 1){ if (tid < st) red[tid] += red[tid + st]; __syncthreads(); }
    float var = red[0] / DD - mean * mean;
    float rstd = rsqrtf(var + EPSV);
    __syncthreads();
    for (int i = tid; i < DD; i += 256) cn[i] = (e[i] - mean) * rstd * gamma_g[i] + beta_g[i];
    __syncthreads();
    for (int c = tid; c < CC; c += 256){
      const float* w = Wg + (size_t)c * DD;
      float a = 0.f;
      #pragma unroll 8
      for (int d = 0; d < DD; d++) a += cn[d] * w[d];
      gsh[c] = a;
    }
    __syncthreads();
    if (tid < NHEAD){
      float a = 0.f;
      for (int d = 0; d < HDIM; d++){ float v = gsh[tid * HDIM + d]; a += v * v; }
      nrm[tid] = fmaxf(sqrtf(a), 1e-12f);
    }
    __syncthreads();
    for (int c = tid; c < CC; c += 256){
      g[(size_t)n * CC + c] = gsh[c];
      gnb[(size_t)n * CC + c] = f2bf(gsh[c] / nrm[c >> 6]);
    }
  }
}

// ---------------- fused LN (single-pass): stage bf16 tile in LDS, stats, apply+transpose ----------------
__global__ __launch_bounds__(256, 2) void fuse_ln_k(const float* __restrict__ X,
    const float* __restrict__ lng, const float* __restrict__ lnb,
    bf16* __restrict__ xnT){
  __shared__ bf16 st[512][68];
  __shared__ float sred[2][4][64];
  __shared__ float muS[64], rsS[64];
  int p0 = blockIdx.x * 64;
  int b = p0 / LL, l0 = p0 - b * LL;
  int tid = threadIdx.x;
  #pragma unroll 4
  for (int i = 0; i < 32; i++){
    int idx = i * 256 + tid;
    int c = idx >> 4, l4 = (idx & 15) * 4;
    float4 v = *reinterpret_cast<const float4*>(X + (size_t)b * CC * LL + (size_t)c * LL + l0 + l4);
    short4v pk;
    pk[0] = bfbits(v.x); pk[1] = bfbits(v.y); pk[2] = bfbits(v.z); pk[3] = bfbits(v.w);
    *(short4v*)&st[c][l4] = pk;
  }
  __syncthreads();
  {
    int cg = tid >> 6, l = tid & 63;
    float s = 0.f, ss = 0.f;
    for (int c = cg * 128; c < cg * 128 + 128; c++){
      float v = bf2f(st[c][l]);
      s += v; ss += v * v;
    }
    sred[0][cg][l] = s; sred[1][cg][l] = ss;
  }
  __syncthreads();
  if (tid < 64){
    float st2 = sred[0][0][tid] + sred[0][1][tid] + sred[0][2][tid] + sred[0][3][tid];
    float sst = sred[1][0][tid] + sred[1][1][tid] + sred[1][2][tid] + sred[1][3][tid];
    float m = st2 * (1.0f / CC);
    float var = sst * (1.0f / CC) - m * m;
    muS[tid] = m; rsS[tid] = rsqrtf(var + EPSV);
  }
  __syncthreads();
  int pr = tid >> 4;
  int cc = (tid & 15) * 4;
  for (int cb = 0; cb < 8; cb++){
    int c0 = cb * 64;
    #pragma unroll
    for (int i = 0; i < 4; i++){
      int pl = pr + i * 16;
      int p = p0 + pl;
      float m = muS[pl], r = rsS[pl];
      short4v pk;
      #pragma unroll
      for (int e = 0; e < 4; e++){
        int c = c0 + cc + e;
        pk[e] = bfbits((bf2f(st[c][pl]) - m) * r * lng[c] + lnb[c]);
      }
      *(short4v*)&xnT[(size_t)p * CC + c0 + cc] = pk;
    }
  }
}

// ---------------- bf16 MFMA GEMM (reg-staged, XOR-swizzled LDS) ----------------
// MODE 0 (1D grid 3464): q -> qT pixel-major + rq + qssp + FUSED gm1 (gnb@q from T, pmin/pmax) ;
//                        k [b][c][l] + kssp + segp ; v -> vT ; blocks>=3456: clsobj
// MODE 1: xT = bf16(img + C + bo) + LN stat partials (statp write)
// MODE 2: h = gelu(C+b1), B = xT with inline LN (stats derived from statp)
// MODE 3: d_out = xT + C + b2
// gm1 partials use TRANSPOSED layout [bh][GMBLK][128 n] (64B-contiguous wave writes).
// launch_bounds(256,3): 3 blocks/CU (136 total regs/wave <= ~170 budget; 107KB LDS).
template<int MODE>
__global__ __launch_bounds__(256, 3) void mgemm_k(
    const bf16* __restrict__ A,
    const bf16* __restrict__ B,
    const float* __restrict__ residf,
    const bf16* __restrict__ residb,
    const float* __restrict__ bias,
    const float* __restrict__ lng, const float* __restrict__ lnb,
    float2* __restrict__ statp,
    float* __restrict__ qssp, float* __restrict__ kssp,
    bf16* __restrict__ qTo, float* __restrict__ rqo,
    bf16* __restrict__ ko, bf16* __restrict__ vo,
    bf16* __restrict__ xT_out,
    float* __restrict__ xo,
    bf16* __restrict__ ho,
    const float* __restrict__ gA, const float* __restrict__ clsl, float* __restrict__ clsovO,
    const float* __restrict__ segf, float* __restrict__ segpO,
    const bf16* __restrict__ gnbA, float* __restrict__ pminO, float* __restrict__ pmaxO)
{
  __shared__ __align__(16) short smem[128 * TP];
  __shared__ float sredf[512];
  short* Asm = smem;
  short* Bsm = smem + 8192;
  short* T   = smem;
  int tid = threadIdx.x;
  if (MODE == 0 && blockIdx.x >= 3456){
    int idx = (blockIdx.x - 3456) * 256 + tid;
    int b = idx >> 9, c = idx & 511;
    float a = 0.f;
    for (int n = 0; n < NCLS; n++) a += gA[(size_t)n * CC + c] * clsl[b * NCLS + n];
    clsovO[idx] = a;
    return;
  }
  int lane = tid & 63, wv = tid >> 6;
  int wr = wv >> 1, wc = wv & 1;
  int r15 = lane & 15, g = lane >> 4, h7 = lane & 7;
  int flat, gx, cpx;
  if (MODE == 0){ flat = blockIdx.x; gx = 12; cpx = 432; }
  else { gx = gridDim.x; flat = blockIdx.y * gx + blockIdx.x; cpx = (gx * gridDim.y) >> 3; }
  int swz = (flat & 7) * cpx + (flat >> 3);
  int m0 = (swz % gx) * 128, n0 = (swz / gx) * 128;
  int srow = tid >> 3, skkg = tid & 7;
  int sslot = ((skkg ^ (srow & 7))) * 8;

  f32x4 acc[4][4];
  #pragma unroll
  for (int i = 0; i < 4; i++)
    #pragma unroll
    for (int j = 0; j < 4; j++) acc[i][j] = (f32x4){0.f, 0.f, 0.f, 0.f};

  if (MODE == 2){
    if (tid < 128){
      int p = n0 + tid;
      float s = 0.f, ss2 = 0.f;
      #pragma unroll
      for (int part = 0; part < 4; part++){
        float2 v = statp[part * BLPIX + p];
        s += v.x; ss2 += v.y;
      }
      float m = s * (1.0f / CC);
      float var = ss2 * (1.0f / CC) - m * m;
      sredf[tid] = m;
      sredf[128 + tid] = rsqrtf(var + EPSV);
    }
    __syncthreads();
  }

  short8v pa[4], pb[4];
  auto loadAB = [&](int it){
    int k0 = it * 64;
    if (MODE == 2){
      int c0 = k0 + skkg * 8;
      float ga[8], be[8];
      *(float4*)&ga[0] = *(const float4*)&lng[c0];
      *(float4*)&ga[4] = *(const float4*)&lng[c0 + 4];
      *(float4*)&be[0] = *(const float4*)&lnb[c0];
      *(float4*)&be[4] = *(const float4*)&lnb[c0 + 4];
      #pragma unroll
      for (int r = 0; r < 4; r++){
        pa[r] = *reinterpret_cast<const short8v*>(A + (size_t)(m0 + r * 32 + srow) * 512 + c0);
        int rl = r * 32 + srow;
        float mm = sredf[rl], rr = sredf[128 + rl];
        short8v rawv = *reinterpret_cast<const short8v*>(B + (size_t)(n0 + rl) * 512 + c0);
        short8v ov;
        #pragma unroll
        for (int e = 0; e < 8; e++){
          float v = (s2f(rawv[e]) - mm) * rr * ga[e] + be[e];
          ov[e] = bfbits(v);
        }
        pb[r] = ov;
      }
    } else {
      #pragma unroll
      for (int r = 0; r < 4; r++){
        pa[r] = *reinterpret_cast<const short8v*>(A + (size_t)(m0 + r * 32 + srow) * 512 + k0 + skkg * 8);
        pb[r] = *reinterpret_cast<const short8v*>(B + (size_t)(n0 + r * 32 + srow) * 512 + k0 + skkg * 8);
      }
    }
  };

  loadAB(0);
  for (int it = 0; it < 8; ++it){
    __syncthreads();
    #pragma unroll
    for (int r = 0; r < 4; r++){
      int row = r * 32 + srow;
      *(short8v*)&Asm[row * 64 + sslot] = pa[r];
      *(short8v*)&Bsm[row * 64 + sslot] = pb[r];
    }
    __syncthreads();
    if (it < 7) loadAB(it + 1);
    #pragma unroll
    for (int s = 0; s < 2; s++){
      int slot = ((s * 4 + g) ^ h7) * 8;
      short8v af[4], bf_[4];
      #pragma unroll
      for (int i = 0; i < 4; i++){
        af[i]  = *(const short8v*)&Asm[(wr * 64 + i * 16 + r15) * 64 + slot];
        bf_[i] = *(const short8v*)&Bsm[(wc * 64 + i * 16 + r15) * 64 + slot];
      }
      #pragma unroll
      for (int i = 0; i < 4; i++)
        #pragma unroll
        for (int j = 0; j < 4; j++){
          if (MODE == 2)
            acc[i][j] = __builtin_amdgcn_mfma_f32_16x16x32_bf16(bf_[i], af[j], acc[i][j], 0, 0, 0);
          else
            acc[i][j] = __builtin_amdgcn_mfma_f32_16x16x32_bf16(af[i], bf_[j], acc[i][j], 0, 0, 0);
        }
    }
  }

  int bIdx = n0 / LL;
  int lbase = n0 - bIdx * LL;
  if (MODE == 0){
    int part = m0 >> 9;
    if (part == 0){
      int chb = m0 + wr * 64;
      int head = chb >> 6;
      int bh = bIdx * 8 + head;
      #pragma unroll
      for (int j = 0; j < 4; j++){
        float ssl = 0.f;
        #pragma unroll
        for (int i = 0; i < 4; i++)
          #pragma unroll
          for (int e = 0; e < 4; e++) ssl += acc[i][j][e] * acc[i][j][e];
        ssl += __shfl_xor(ssl, 16); ssl += __shfl_xor(ssl, 32);
        float rqv_ = 1.0f / fmaxf(sqrtf(ssl), 1e-12f);
        if (g == 0){
          int l = lbase + wc * 64 + j * 16 + r15;
          rqo[(size_t)bh * LL + l] = rqv_;
          sredf[256 + wr * 128 + wc * 64 + j * 16 + r15] = rqv_;
        }
      }
      #pragma unroll
      for (int i = 0; i < 4; i++)
        #pragma unroll
        for (int e = 0; e < 4; e++){
          float ssv = acc[i][0][e]*acc[i][0][e] + acc[i][1][e]*acc[i][1][e]
                    + acc[i][2][e]*acc[i][2][e] + acc[i][3][e]*acc[i][3][e];
          #pragma unroll
          for (int msk = 1; msk < 16; msk <<= 1) ssv += __shfl_xor(ssv, msk);
          if (r15 == 0) sredf[wv * 64 + i * 16 + g * 4 + e] = ssv;
        }
      __syncthreads();
      if (tid < 128){
        int wrr = tid >> 6, chL = tid & 63;
        float tot = sredf[(wrr * 2) * 64 + chL] + sredf[(wrr * 2 + 1) * 64 + chL];
        int c = m0 + wrr * 64 + chL;
        int row = bIdx * 512 + c;
        int ltile = lbase >> 7;
        qssp[(size_t)row * NLT + ltile] = tot;
      }
      #pragma unroll
      for (int i = 0; i < 4; i++)
        #pragma unroll
        for (int j = 0; j < 4; j++){
          int pxl = wc * 64 + j * 16 + r15;
          int chl = wr * 64 + i * 16 + g * 4;
          short4v pk;
          #pragma unroll
          for (int e = 0; e < 4; e++) pk[e] = bfbits(acc[i][j][e]);
          *(short4v*)&T[pxl * TP + chl] = pk;
        }
      __syncthreads();
      #pragma unroll
      for (int it2 = 0; it2 < 16; it2++){
        int c2 = tid + it2 * 256;
        int px = c2 >> 5, ch4 = (c2 & 31) * 4;
        *(short4v*)&qTo[((size_t)bIdx * LL + lbase + px) * CC + m0 + ch4] = *(short4v*)&T[px * TP + ch4];
      }
      // ---- fused gm1: gnb[128n x 64d] @ q (B-frags straight from T) -> pmin/pmax partials
      //      transposed layout [bh][GMBLK][128 n]: wave writes are 64B-contiguous ----
      {
        int h0 = m0 >> 6;          // 0,2,4,6 : first of the 2 heads in this ch-tile
        int ltb = lbase >> 6;      // base 64-px tile index (even)
        #pragma unroll
        for (int hh = 0; hh < 2; hh++){
          int bh2 = bIdx * 8 + h0 + hh;
          short8v ag2[2][2];
          #pragma unroll
          for (int i = 0; i < 2; i++)
            #pragma unroll
            for (int kt = 0; kt < 2; kt++)
              ag2[i][kt] = *reinterpret_cast<const short8v*>(gnbA + (size_t)(wv * 32 + i * 16 + r15) * CC + (h0 + hh) * 64 + kt * 32 + g * 8);
          #pragma unroll
          for (int ph = 0; ph < 2; ph++){
            short8v bq2[4][2];
            float rqv2[4];
            #pragma unroll
            for (int j = 0; j < 4; j++){
              #pragma unroll
              for (int kt = 0; kt < 2; kt++)
                bq2[j][kt] = *reinterpret_cast<const short8v*>(&T[(ph * 64 + j * 16 + r15) * TP + hh * 64 + kt * 32 + g * 8]);
              rqv2[j] = sredf[256 + hh * 128 + ph * 64 + j * 16 + r15];
            }
            f32x4 acc2[2][4];
            #pragma unroll
            for (int i = 0; i < 2; i++)
              #pragma unroll
              for (int j = 0; j < 4; j++) acc2[i][j] = (f32x4){0.f,0.f,0.f,0.f};
            #pragma unroll
            for (int kt = 0; kt < 2; kt++)
              #pragma unroll
              for (int i = 0; i < 2; i++)
                #pragma unroll
                for (int j = 0; j < 4; j++)
                  acc2[i][j] = __builtin_amdgcn_mfma_f32_16x16x32_bf16(ag2[i][kt], bq2[j][kt], acc2[i][j], 0, 0, 0);
            size_t pbase = ((size_t)bh2 * GMBLK + ltb + ph) * 128;
            #pragma unroll
            for (int i = 0; i < 2; i++)
              #pragma unroll
              for (int e = 0; e < 4; e++){
                float mn = 1e30f, mx = -1e30f;
                #pragma unroll
                for (int j = 0; j < 4; j++){
                  float v = acc2[i][j][e] * rqv2[j];
                  mn = fminf(mn, v); mx = fmaxf(mx, v);
                }
                #pragma unroll
                for (int msk = 1; msk < 16; msk <<= 1){
                  mn = fminf(mn, __shfl_xor(mn, msk));
                  mx = fmaxf(mx, __shfl_xor(mx, msk));
                }
                if (r15 == 0){
                  int n = wv * 32 + i * 16 + g * 4 + e;
                  pminO[pbase + n] = mn;
                  pmaxO[pbase + n] = mx;
                }
              }
          }
        }
      }
    } else if (part == 1){
      int chb = (m0 & 511) + wr * 64;
      #pragma unroll
      for (int i = 0; i < 4; i++)
        #pragma unroll
        for (int j = 0; j < 4; j++){
          int l = lbase + wc * 64 + j * 16 + r15;
          #pragma unroll
          for (int e = 0; e < 4; e++){
            int ch = chb + i * 16 + g * 4 + e;
            ko[(size_t)bIdx * CC * LL + (size_t)ch * LL + l] = f2bf(acc[i][j][e]);
          }
        }
      // sigmoid(seg) weights for this thread's 4 l's (fp32 acc = pre-rounded k)
      float sg[4];
      #pragma unroll
      for (int j = 0; j < 4; j++){
        int l = lbase + wc * 64 + j * 16 + r15;
        sg[j] = 1.0f / (1.0f + expf(-segf[(size_t)bIdx * LL + l]));
      }
      #pragma unroll
      for (int i = 0; i < 4; i++)
        #pragma unroll
        for (int e = 0; e < 4; e++){
          float ssv = acc[i][0][e]*acc[i][0][e] + acc[i][1][e]*acc[i][1][e]
                    + acc[i][2][e]*acc[i][2][e] + acc[i][3][e]*acc[i][3][e];
          float sgv = sg[0]*acc[i][0][e] + sg[1]*acc[i][1][e]
                    + sg[2]*acc[i][2][e] + sg[3]*acc[i][3][e];
          #pragma unroll
          for (int msk = 1; msk < 16; msk <<= 1){
            ssv += __shfl_xor(ssv, msk);
            sgv += __shfl_xor(sgv, msk);
          }
          if (r15 == 0){
            sredf[wv * 64 + i * 16 + g * 4 + e] = ssv;
            sredf[256 + wv * 64 + i * 16 + g * 4 + e] = sgv;
          }
        }
      __syncthreads();
      if (tid < 128){
        int wrr = tid >> 6, chL = tid & 63;
        float tot  = sredf[(wrr * 2) * 64 + chL] + sredf[(wrr * 2 + 1) * 64 + chL];
        float tots = sredf[256 + (wrr * 2) * 64 + chL] + sredf[256 + (wrr * 2 + 1) * 64 + chL];
        int c = (m0 & 511) + wrr * 64 + chL;
        int row = bIdx * 512 + c;
        int ltile = lbase >> 7;
        kssp[(size_t)row * NLT + ltile] = tot;
        segpO[(size_t)row * NLT + ltile] = tots;
      }
    } else {
      __syncthreads();
      #pragma unroll
      for (int i = 0; i < 4; i++)
        #pragma unroll
        for (int j = 0; j < 4; j++){
          int pxl = wc * 64 + j * 16 + r15;
          int chl = wr * 64 + i * 16 + g * 4;
          short4v pk;
          #pragma unroll
          for (int e = 0; e < 4; e++) pk[e] = bfbits(acc[i][j][e]);
          *(short4v*)&T[pxl * TP + chl] = pk;
        }
      __syncthreads();
      int chg = (m0 & 511);
      #pragma unroll
      for (int it2 = 0; it2 < 16; it2++){
        int c2 = tid + it2 * 256;
        int px = c2 >> 5, ch4 = (c2 & 31) * 4;
        *(short4v*)&vo[((size_t)bIdx * LL + lbase + px) * CC + chg + ch4] = *(short4v*)&T[px * TP + ch4];
      }
    }
  } else if (MODE == 1){
    __syncthreads();
    float sj[4] = {0.f,0.f,0.f,0.f}, ssj[4] = {0.f,0.f,0.f,0.f};
    #pragma unroll
    for (int i = 0; i < 4; i++)
      #pragma unroll
      for (int j = 0; j < 4; j++){
        int l = lbase + wc * 64 + j * 16 + r15;
        int chm = m0 + wr * 64 + i * 16 + g * 4;
        int pxl = wc * 64 + j * 16 + r15;
        int chl = wr * 64 + i * 16 + g * 4;
        short4v pk;
        #pragma unroll
        for (int e = 0; e < 4; e++){
          int m = chm + e;
          size_t o = (size_t)bIdx * CC * LL + (size_t)m * LL + l;
          float xv = residf[o] + acc[i][j][e] + bias[m];
          pk[e] = bfbits(xv);
          sj[j] += xv; ssj[j] += xv * xv;
        }
        *(short4v*)&T[pxl * TP + chl] = pk;
      }
    #pragma unroll
    for (int j = 0; j < 4; j++){
      sj[j] += __shfl_xor(sj[j], 16); sj[j] += __shfl_xor(sj[j], 32);
      ssj[j] += __shfl_xor(ssj[j], 16); ssj[j] += __shfl_xor(ssj[j], 32);
    }
    if (g == 0){
      #pragma unroll
      for (int j = 0; j < 4; j++){
        sredf[wv * 128 + j * 32 + r15 * 2 + 0] = sj[j];
        sredf[wv * 128 + j * 32 + r15 * 2 + 1] = ssj[j];
      }
    }
    __syncthreads();
    if (tid < 128){
      int wv2 = tid >> 6, lane2 = tid & 63, j2 = lane2 >> 4, r2 = lane2 & 15;
      float s   = sredf[wv2 * 128 + j2 * 32 + r2 * 2 + 0] + sredf[(wv2 + 2) * 128 + j2 * 32 + r2 * 2 + 0];
      float ss2 = sredf[wv2 * 128 + j2 * 32 + r2 * 2 + 1] + sredf[(wv2 + 2) * 128 + j2 * 32 + r2 * 2 + 1];
      int p = n0 + wv2 * 64 + j2 * 16 + r2;
      statp[(m0 >> 7) * BLPIX + p] = make_float2(s, ss2);
    }
    #pragma unroll
    for (int it2 = 0; it2 < 16; it2++){
      int c2 = tid + it2 * 256;
      int px = c2 >> 5, ch4 = (c2 & 31) * 4;
      *(short4v*)&xT_out[((size_t)bIdx * LL + lbase + px) * CC + m0 + ch4] = *(short4v*)&T[px * TP + ch4];
    }
  } else if (MODE == 3){
    __syncthreads();
    #pragma unroll
    for (int it2 = 0; it2 < 16; it2++){
      int c2 = tid + it2 * 256;
      int px = c2 >> 5, ch4 = (c2 & 31) * 4;
      *(short4v*)&T[px * TP + ch4] = *(const short4v*)&residb[((size_t)bIdx * LL + lbase + px) * CC + m0 + ch4];
    }
    __syncthreads();
    #pragma unroll
    for (int i = 0; i < 4; i++)
      #pragma unroll
      for (int j = 0; j < 4; j++){
        int l = lbase + wc * 64 + j * 16 + r15;
        int chm = m0 + wr * 64 + i * 16 + g * 4;
        int pxl = wc * 64 + j * 16 + r15;
        int chl = wr * 64 + i * 16 + g * 4;
        short4v rv = *(short4v*)&T[pxl * TP + chl];
        #pragma unroll
        for (int e = 0; e < 4; e++){
          int m = chm + e;
          size_t o = (size_t)bIdx * CC * LL + (size_t)m * LL + l;
          xo[o] = s2f(rv[e]) + acc[i][j][e] + bias[m];
        }
      }
  } else {
    #pragma unroll
    for (int i = 0; i < 4; i++)
      #pragma unroll
      for (int j = 0; j < 4; j++){
        int mm = m0 + wr * 64 + j * 16 + r15;
        float bv = bias[mm];
        #pragma unroll
        for (int e = 0; e < 4; e++){
          int n = n0 + wc * 64 + i * 16 + g * 4 + e;
          float t = acc[i][j][e] + bv;
          float gv = 0.5f * t * (1.0f + erff(t * 0.70710678118654752f));
          ho[(size_t)n * CC + mm] = f2bf(gv);
        }
      }
  }
}

// ================= mega1: attn(qT-staged) | segden | qn/kn/segn red =================
// [0,256) attn ; [256,260) segden ; [260,1796) red (6144 rows)
__global__ __launch_bounds__(256) void mega1_k(
    const bf16* __restrict__ qT, const float* __restrict__ rq,
    const bf16* __restrict__ k, const bf16* __restrict__ gnb,
    float* __restrict__ pmin, float* __restrict__ pmax,
    float* __restrict__ part,
    const float* __restrict__ seg, float* __restrict__ seg_num, float* __restrict__ den,
    const float* __restrict__ qssp, const float* __restrict__ kssp,
    const float* __restrict__ segp,
    float* __restrict__ qn, float* __restrict__ kn)
{
  __shared__ __align__(16) bf16 qs[128 * 68];
  int bid = blockIdx.x;
  int t = threadIdx.x;
  (void)rq; (void)gnb; (void)pmin; (void)pmax;
  if (bid < 256){
    int ls = bid & 7, bh = bid >> 3;
    int b = bh >> 3, h = bh & 7;
    int w = t >> 6, lane = t & 63, r15 = lane & 15, g = lane >> 4;
    const bf16* kp = k + (size_t)b * CC * LL + (size_t)h * HDIM * LL;
    f32x4 acc4[4];
    #pragma unroll
    for (int j = 0; j < 4; j++) acc4[j] = (f32x4){0.f,0.f,0.f,0.f};
    for (int stg = 0; stg < 9; stg++){
      int lb = ls * 1152 + stg * 128;
      #pragma unroll
      for (int it = 0; it < 8; it++){
        int idx = t + it * 256;
        int row = idx >> 4, c4 = (idx & 15) * 4;
        *(short4v*)&qs[row * 68 + c4] = *(const short4v*)&qT[((size_t)(b * LL + lb + row)) * CC + h * 64 + c4];
      }
      __syncthreads();
      #pragma unroll
      for (int kstep = 0; kstep < 4; kstep++){
        int lloc = kstep * 32 + g * 8;
        short8v aq;
        #pragma unroll
        for (int jj = 0; jj < 8; jj++)
          aq[jj] = *reinterpret_cast<short*>(&qs[(lloc + jj) * 68 + w * 16 + r15]);
        int koff = lb + kstep * 32 + g * 8;
        short8v bk[4];
        #pragma unroll
        for (int j = 0; j < 4; j++) bk[j] = *reinterpret_cast<const short8v*>(kp + (size_t)(j * 16 + r15) * LL + koff);
        #pragma unroll
        for (int j = 0; j < 4; j++)
          acc4[j] = __builtin_amdgcn_mfma_f32_16x16x32_bf16(aq, bk[j], acc4[j], 0, 0, 0);
      }
      __syncthreads();
    }
    #pragma unroll
    for (int j = 0; j < 4; j++)
      #pragma unroll
      for (int e = 0; e < 4; e++){
        int d = w * 16 + g * 4 + e;
        int ee = j * 16 + r15;
        part[((size_t)(bh * LSPLIT + ls)) * 4096 + d * 64 + ee] = acc4[j][e];
      }
    return;
  }
  if (bid < 260){
    float* red = (float*)qs;
    int b = bid - 256;
    const float* sp = seg + (size_t)b * LL;
    float s = 0.f;
    for (int i = t; i < LL; i += 256) s += 1.0f / (1.0f + expf(-sp[i]));
    red[t] = s; __syncthreads();
    for (int st = 128; st > 0; st >>= 1){ if (t < st) red[t] += red[t + st]; __syncthreads(); }
    if (t == 0) den[b] = red[0];
    return;
  }
  {
    int r4 = (bid - 260) * 4 + (t >> 6);
    int lane = t & 63;
    const float* src = (r4 < 2048) ? qssp : ((r4 < 4096) ? kssp : segp);
    int r = r4 & 2047;
    float s = src[(size_t)r * NLT + lane] + ((lane < 8) ? src[(size_t)r * NLT + 64 + lane] : 0.f);
    #pragma unroll
    for (int m = 1; m < 64; m <<= 1) s += __shfl_xor(s, m);
    if (lane == 0){
      if (r4 < 2048) qn[r] = fmaxf(sqrtf(s), 1e-12f);
      else if (r4 < 4096) kn[r] = fmaxf(sqrtf(s), 1e-12f);
      else seg_num[r] = s;
    }
  }
}

// ---------------- aux (+obj inline, staged k tile) ----------------
__global__ __launch_bounds__(256) void aux_k(const bf16* __restrict__ k,
                      const float* __restrict__ clsov, const float* __restrict__ segn,
                      const float* __restrict__ segd,
                      float* __restrict__ aux,
                      float* __restrict__ pmin, float* __restrict__ pmax){
  __shared__ bf16 ks[64 * 68];
  __shared__ float os[64];
  __shared__ float sspart[4][64], dotpart[4][64];
  int bh = blockIdx.x, lt = blockIdx.y;
  int l0 = lt * 64;
  int t = threadIdx.x;
  int b = bh >> 3, h = bh & 7;
  const bf16* kp = k + (size_t)b * CC * LL + (size_t)h * HDIM * LL + l0;
  #pragma unroll
  for (int i2 = 0; i2 < 4; i2++){
    int idx = t + i2 * 256;
    int d = idx >> 4, lch = (idx & 15) * 4;
    *(short4v*)&ks[d * 68 + lch] = *reinterpret_cast<const short4v*>(kp + (size_t)d * LL + lch);
  }
  if (t < 64){
    float sv = clsov[bh * 64 + t] + segn[bh * 64 + t] / segd[b];
    float ss2 = sv * sv;
    #pragma unroll
    for (int m = 1; m < 64; m <<= 1) ss2 += __shfl_xor(ss2, m);
    os[t] = sv / fmaxf(sqrtf(ss2), 1e-12f);
  }
  __syncthreads();
  {
    int dg = t >> 6, l = t & 63;
    float ssk = 0.f, dk = 0.f;
    #pragma unroll
    for (int dd = 0; dd < 16; dd++){
      float v = bf2f(ks[(dg * 16 + dd) * 68 + l]);
      ssk += v * v; dk += os[dg * 16 + dd] * v;
    }
    sspart[dg][l] = ssk; dotpart[dg][l] = dk;
  }
  __syncthreads();
  if (t < 64){
    float ss = sspart[0][t] + sspart[1][t] + sspart[2][t] + sspart[3][t];
    float dot = dotpart[0][t] + dotpart[1][t] + dotpart[2][t] + dotpart[3][t];
    float av = dot / fmaxf(sqrtf(ss), 1e-12f);
    aux[(size_t)bh * LL + l0 + t] = av;
    float mn = av, mx = av;
    #pragma unroll
    for (int m = 1; m < 64; m <<= 1){
      mn = fminf(mn, __shfl_xor(mn, m));
      mx = fmaxf(mx, __shfl_xor(mx, m));
    }
    if (t == 0){ pmin[bh * AUXBLK + lt] = mn; pmax[bh * AUXBLK + lt] = mx; }
  }
}

// ================= megared: gmred(transposed partials) | auxred | smax =================
__global__ __launch_bounds__(256) void megared_k(
    const float* __restrict__ gpmin, const float* __restrict__ gpmax,
    float* __restrict__ gmin, float* __restrict__ gms,
    const float* __restrict__ apmin, const float* __restrict__ apmax,
    float* __restrict__ amin, float* __restrict__ ams,
    const float* __restrict__ part, const float* __restrict__ qn,
    const float* __restrict__ kn, const float* __restrict__ scale,
    bf16* __restrict__ Pb)
{
  __shared__ float As[64 * 65];
  int bid = blockIdx.x;
  int tid = threadIdx.x;
  if (bid < 1024){
    int row = bid * 4 + (tid >> 6);
    int lane = tid & 63;
    int bh = row >> 7, n = row & 127;
    const float* pb_ = gpmin + (size_t)bh * GMBLK * 128 + n;
    const float* px_ = gpmax + (size_t)bh * GMBLK * 128 + n;
    float mn = pb_[(size_t)lane * 128];
    float mx = px_[(size_t)lane * 128];
    mn = fminf(mn, pb_[(size_t)(64 + lane) * 128]);
    mx = fmaxf(mx, px_[(size_t)(64 + lane) * 128]);
    if (lane < 16){
      mn = fminf(mn, pb_[(size_t)(128 + lane) * 128]);
      mx = fmaxf(mx, px_[(size_t)(128 + lane) * 128]);
    }
    #pragma unroll
    for (int m = 1; m < 64; m <<= 1){
      mn = fminf(mn, __shfl_xor(mn, m));
      mx = fmaxf(mx, __shfl_xor(mx, m));
    }
    if (lane == 0){ gmin[row] = mn; gms[row] = mx - mn; }
    return;
  }
  if (bid < 1032){
    int bh = (bid - 1024) * 4 + (tid >> 6);
    int lane = tid & 63;
    float mn = apmin[bh * AUXBLK + lane];
    float mx = apmax[bh * AUXBLK + lane];
    mn = fminf(mn, apmin[bh * AUXBLK + 64 + lane]);
    mx = fmaxf(mx, apmax[bh * AUXBLK + 64 + lane]);
    if (lane < 16){
      mn = fminf(mn, apmin[bh * AUXBLK + 128 + lane]);
      mx = fmaxf(mx, apmax[bh * AUXBLK + 128 + lane]);
    }
    #pragma unroll
    for (int m = 1; m < 64; m <<= 1){
      mn = fminf(mn, __shfl_xor(mn, m));
      mx = fmaxf(mx, __shfl_xor(mx, m));
    }
    if (lane == 0){ amin[bh] = mn; ams[bh] = mx - mn; }
    return;
  }
  {
    int bh = bid - 1032;
    int h = bh & 7;
    #pragma unroll
    for (int i = 0; i < 16; i++){
      int cell = tid + i * 256;
      int d = cell >> 6, e = cell & 63;
      float s = 0.f;
      #pragma unroll
      for (int ls = 0; ls < LSPLIT; ls++) s += part[((size_t)(bh * LSPLIT + ls)) * 4096 + cell];
      As[d * 65 + e] = s * scale[h] / (qn[bh * 64 + d] * kn[bh * 64 + e]);
    }
    __syncthreads();
    if (tid < 64){
      int d = tid;
      float mx = -1e30f;
      for (int e = 0; e < 64; e++) mx = fmaxf(mx, As[d * 65 + e]);
      float sum = 0.f;
      for (int e = 0; e < 64; e++){ float ev = expf(As[d * 65 + e] - mx); As[d * 65 + e] = ev; sum += ev; }
      float inv = 1.0f / sum;
      for (int e = 0; e < 64; e++) Pb[(size_t)bh * 4096 + d * 64 + e] = f2bf(As[d * 65 + e] * inv);
    }
  }
}

// ---------------- pv (MFMA, qT-based) ----------------
__global__ __launch_bounds__(256) void pv_k(const bf16* __restrict__ qT, const float* __restrict__ rq,
      const bf16* __restrict__ gnb,
      const float* __restrict__ aux,
      const float* __restrict__ gmin, const float* __restrict__ gms,
      const float* __restrict__ amin, const float* __restrict__ ams,
      const bf16* __restrict__ Pb, const bf16* __restrict__ vT, bf16* __restrict__ outT){
  __shared__ float gminS[128], rgmsS[128];
  __shared__ float separt[4][64], setpart[4][64];
  __shared__ float wl[64];
  int bh = blockIdx.x, lt = blockIdx.y;
  int l0 = lt * 64;
  int t = threadIdx.x;
  int b = bh >> 3, h = bh & 7;
  int w = t >> 6, lane = t & 63, r15 = lane & 15, g = lane >> 4;
  if (t < 128){ gminS[t] = gmin[bh * 128 + t]; rgmsS[t] = 1.0f / gms[bh * 128 + t]; }
  short8v ag[2][2];
  #pragma unroll
  for (int i = 0; i < 2; i++)
    #pragma unroll
    for (int kt = 0; kt < 2; kt++)
      ag[i][kt] = *reinterpret_cast<const short8v*>(gnb + (size_t)(w * 32 + i * 16 + r15) * CC + h * 64 + kt * 32 + g * 8);
  const bf16* qTp = qT + ((size_t)(b * LL + l0)) * CC + h * 64;
  short8v bq[4][2];
  float rqv[4];
  #pragma unroll
  for (int j = 0; j < 4; j++){
    #pragma unroll
    for (int kt = 0; kt < 2; kt++)
      bq[j][kt] = *reinterpret_cast<const short8v*>(qTp + (size_t)(j * 16 + r15) * CC + kt * 32 + g * 8);
    rqv[j] = rq[(size_t)bh * LL + l0 + j * 16 + r15];
  }
  f32x4 acc[2][4];
  #pragma unroll
  for (int i = 0; i < 2; i++)
    #pragma unroll
    for (int j = 0; j < 4; j++) acc[i][j] = (f32x4){0.f,0.f,0.f,0.f};
  #pragma unroll
  for (int kt = 0; kt < 2; kt++)
    #pragma unroll
    for (int i = 0; i < 2; i++)
      #pragma unroll
      for (int j = 0; j < 4; j++)
        acc[i][j] = __builtin_amdgcn_mfma_f32_16x16x32_bf16(ag[i][kt], bq[j][kt], acc[i][j], 0, 0, 0);
  __syncthreads();
  float seL[4] = {0.f,0.f,0.f,0.f}, setL[4] = {0.f,0.f,0.f,0.f};
  #pragma unroll
  for (int i = 0; i < 2; i++)
    #pragma unroll
    for (int j = 0; j < 4; j++)
      #pragma unroll
      for (int e = 0; e < 4; e++){
        int n = w * 32 + i * 16 + g * 4 + e;
        float tt = (acc[i][j][e] * rqv[j] - gminS[n]) * rgmsS[n];
        float ee = __expf(tt);
        seL[j] += ee; setL[j] += ee * tt;
      }
  #pragma unroll
  for (int j = 0; j < 4; j++){
    seL[j] += __shfl_xor(seL[j], 16); seL[j] += __shfl_xor(seL[j], 32);
    setL[j] += __shfl_xor(setL[j], 16); setL[j] += __shfl_xor(setL[j], 32);
  }
  if (g == 0){
    #pragma unroll
    for (int j = 0; j < 4; j++){ separt[w][j * 16 + r15] = seL[j]; setpart[w][j * 16 + r15] = setL[j]; }
  }
  __syncthreads();
  if (t < 64){
    float se = separt[0][t] + separt[1][t] + separt[2][t] + separt[3][t];
    float st = setpart[0][t] + setpart[1][t] + setpart[2][t] + setpart[3][t];
    float gmred = st / se;
    float auxn = (aux[(size_t)bh * LL + l0 + t] - amin[bh]) / ams[bh];
    wl[t] = gmred * auxn;
  }
  __syncthreads();
  short8v ap[4][2];
  #pragma unroll
  for (int i = 0; i < 4; i++)
    #pragma unroll
    for (int kt = 0; kt < 2; kt++)
      ap[i][kt] = *reinterpret_cast<const short8v*>(Pb + (size_t)bh * 4096 + (i * 16 + r15) * 64 + kt * 32 + g * 8);
  const bf16* vrow = vT + ((size_t)b * LL + l0 + w * 16 + r15) * CC + h * 64;
  short8v bv[2];
  #pragma unroll
  for (int kt = 0; kt < 2; kt++) bv[kt] = *reinterpret_cast<const short8v*>(vrow + kt * 32 + g * 8);
  f32x4 oacc[4];
  #pragma unroll
  for (int i = 0; i < 4; i++) oacc[i] = (f32x4){0.f,0.f,0.f,0.f};
  #pragma unroll
  for (int kt = 0; kt < 2; kt++)
    #pragma unroll
    for (int i = 0; i < 4; i++)
      oacc[i] = __builtin_amdgcn_mfma_f32_16x16x32_bf16(ap[i][kt], bv[kt], oacc[i], 0, 0, 0);
  float wlv = wl[w * 16 + r15];
  bf16* orow = outT + ((size_t)b * LL + l0 + w * 16 + r15) * CC + h * 64;
  #pragma unroll
  for (int i = 0; i < 4; i++){
    short4v pk;
    #pragma unroll
    for (int e = 0; e < 4; e++) pk[e] = bfbits(oacc[i][e] * wlv);
    *(short4v*)&orow[i * 16 + g * 4] = pk;
  }
}

extern "C" void kernel_launch(void* const* d_in, const int* in_sizes, int n_in,
                              void* d_out, int out_size, void* d_ws, size_t ws_size,
                              hipStream_t stream){
  const float* img        = (const float*)d_in[0];
  const float* cls_embs   = (const float*)d_in[1];
  const float* cls_logits = (const float*)d_in[2];
  const float* seg        = (const float*)d_in[3];
  const float* gamma_g    = (const float*)d_in[4];
  const float* beta_g     = (const float*)d_in[5];
  const float* gamma_f    = (const float*)d_in[6];
  const float* beta_f     = (const float*)d_in[7];
  const float* attn_scale = (const float*)d_in[8];
  const float* Wg         = (const float*)d_in[9];
  const float* Wqkv       = (const float*)d_in[10];
  const float* Wo         = (const float*)d_in[11];
  const float* bo         = (const float*)d_in[12];
  const float* gamma_n    = (const float*)d_in[13];
  const float* beta_n     = (const float*)d_in[14];
  const float* W1         = (const float*)d_in[15];
  const float* b1         = (const float*)d_in[16];
  const float* W2         = (const float*)d_in[17];
  const float* b2         = (const float*)d_in[18];
  float* outp = (float*)d_out;
  (void)in_sizes; (void)n_in; (void)out_size;

  char* wsb = (char*)d_ws;
  size_t off = 0;
  auto alloc = [&](size_t bytes)->char*{
    char* p = wsb + off;
    off += (bytes + 255) & ~(size_t)255;
    return p;
  };
  float2* statp= (float2*)alloc((size_t)4 * BLPIX * 8);
  float* qssp  = (float*)alloc((size_t)2048 * NLT * 4);
  float* kssp  = (float*)alloc((size_t)2048 * NLT * 4);
  float* segp  = (float*)alloc((size_t)2048 * NLT * 4);
  float* qn    = (float*)alloc(2048 * 4);
  float* kn    = (float*)alloc(2048 * 4);
  float* rqb   = (float*)alloc((size_t)32 * LL * 4);
  float* gbuf  = (float*)alloc((size_t)NCLS * CC * 4);
  bf16*  gnbb  = (bf16*)alloc((size_t)NCLS * CC * 2);
  float* clsov = (float*)alloc(2048 * 4);
  float* segn  = (float*)alloc(2048 * 4);
  float* segd  = (float*)alloc(256);
  float* gminp = (float*)alloc((size_t)32 * 128 * GMBLK * 4);
  float* gmaxp = (float*)alloc((size_t)32 * 128 * GMBLK * 4);
  float* gminv = (float*)alloc(4096 * 4);
  float* gmsv  = (float*)alloc(4096 * 4);
  float* auxv  = (float*)alloc((size_t)32 * LL * 4);
  float* apmin = (float*)alloc(32 * AUXBLK * 4);
  float* apmax = (float*)alloc(32 * AUXBLK * 4);
  float* aminv = (float*)alloc(256);
  float* amsv  = (float*)alloc(256);
  bf16*  Pb    = (bf16*)alloc((size_t)32 * 4096 * 2);
  float* apart = (float*)alloc((size_t)32 * LSPLIT * 4096 * 4);
  bf16* qb    = (bf16*)alloc((size_t)BB * CC * LL * 2);   // holds qT pixel-major
  bf16* kb    = (bf16*)alloc((size_t)BB * CC * LL * 2);
  bf16* wqkvb = (bf16*)alloc((size_t)1536 * 512 * 2);
  bf16* wob   = (bf16*)alloc((size_t)512 * 512 * 2);
  bf16* w1b   = (bf16*)alloc((size_t)512 * 512 * 2);
  bf16* w2b   = (bf16*)alloc((size_t)512 * 512 * 2);
  bf16* vT  = (bf16*)d_out;                                       // [0, 37.75 MB)
  bf16* xnT = (bf16*)((char*)d_out + (size_t)BB * CC * LL * 2);   // [37.75, 75.5 MB)
  bf16* qTb = qb;
  bf16* outT = kb;   // pv output (k dead after attn/aux)
  bf16* xT   = qb;   // x bf16 (qT dead after pv)
  bf16* hbT  = kb;   // MLP hidden (outT dead after MODE1)
  if (off > ws_size) return;

  // 1. wcast | clsg
  wclsg_k<<<1664, 256, 0, stream>>>(Wqkv, Wo, W1, W2, wqkvb, wob, w1b, w2b,
      cls_embs, gamma_g, beta_g, Wg, gbuf, gnbb);
  // 2. fused LN stats+apply+transpose (single img pass)
  fuse_ln_k<<<576, 256, 0, stream>>>(img, gamma_f, beta_f, xnT);
  // 3. qkv GEMM (+qT/rq/qssp/kssp/segp/gm1 epilogues) + clsobj
  mgemm_k<0><<<3464, 256, 0, stream>>>(wqkvb, xnT, nullptr, nullptr, nullptr,
      nullptr, nullptr, nullptr, qssp, kssp,
      qTb, rqb, kb, vT, nullptr, nullptr, nullptr,
      gbuf, cls_logits, clsov, seg, segp,
      gnbb, gminp, gmaxp);
  // 4. attn | segden | qn/kn/segn reduce
  mega1_k<<<1796, 256, 0, stream>>>(qTb, rqb, kb, gnbb, gminp, gmaxp, apart,
      seg, segn, segd, qssp, kssp, segp, qn, kn);
  // 5. aux (+obj)
  aux_k<<<dim3(32, 144), 256, 0, stream>>>(kb, clsov, segn, segd, auxv, apmin, apmax);
  // 6. gmred | auxred | smax
  megared_k<<<1064, 256, 0, stream>>>(gminp, gmaxp, gminv, gmsv,
      apmin, apmax, aminv, amsv,
      apart, qn, kn, attn_scale, Pb);
  // 7. pv
  pv_k<<<dim3(32, GMBLK), 256, 0, stream>>>(qTb, rqb, gnbb, auxv, gminv, gmsv, aminv, amsv, Pb, vT, outT);
  // 8. x = img + Wo@outT + bo -> xT bf16 + LN stat partials
  mgemm_k<1><<<dim3(4, 288), 256, 0, stream>>>(wob, outT, img, nullptr, bo,
      nullptr, nullptr, statp, nullptr, nullptr,
      nullptr, nullptr, nullptr, nullptr, xT, nullptr, nullptr,
      nullptr, nullptr, nullptr, nullptr, nullptr,
      nullptr, nullptr, nullptr);
  // 9. h = gelu(W1 @ LN(xT) + b1)  (stats derived from statp inline)
  mgemm_k<2><<<dim3(4, 288), 256, 0, stream>>>(w1b, xT, nullptr, nullptr, b1,
      gamma_n, beta_n, statp, nullptr, nullptr,
      nullptr, nullptr, nullptr, nullptr, nullptr, nullptr, hbT,
      nullptr, nullptr, nullptr, nullptr, nullptr,
      nullptr, nullptr, nullptr);
  // 10. out = xT + W2 @ h + b2
  mgemm_k<3><<<dim3(4, 288), 256, 0, stream>>>(w2b, hbT, nullptr, xT, b2,
      nullptr, nullptr, nullptr, nullptr, nullptr,
      nullptr, nullptr, nullptr, nullptr, nullptr, outp, nullptr,
      nullptr, nullptr, nullptr, nullptr, nullptr,
      nullptr, nullptr, nullptr);
}

// Round 24
// 432.141 us; speedup vs baseline: 1.0286x; 1.0286x over previous
//
#include <hip/hip_runtime.h>
#include <hip/hip_bf16.h>
#include <math.h>

#define BB 4
#define CC 512
#define NHEAD 8
#define HDIM 64
#define NCLS 128
#define DD 768
#define LL 9216
#define BLPIX 36864
#define EPSV 1e-5f
#define GMBLK 144
#define AUXBLK 144
#define LSPLIT 8
#define NLT 72
#define TP 132   // epilogue transpose-tile pitch (shorts)

typedef __hip_bfloat16 bf16;
typedef __attribute__((ext_vector_type(8))) short short8v;
typedef __attribute__((ext_vector_type(4))) short short4v;
typedef __attribute__((ext_vector_type(4))) float f32x4;

__device__ __forceinline__ float bf2f(bf16 v){ return __bfloat162float(v); }
__device__ __forceinline__ bf16 f2bf(float v){ return __float2bfloat16(v); }
__device__ __forceinline__ short bfbits(float v){ bf16 b = __float2bfloat16(v); return *reinterpret_cast<short*>(&b); }
__device__ __forceinline__ float s2f(short s){ bf16 b = *reinterpret_cast<bf16*>(&s); return __bfloat162float(b); }

// ================= wclsg: wcast | clsg =================
__global__ __launch_bounds__(256) void wclsg_k(
    const float* __restrict__ wqkv, const float* __restrict__ wo,
    const float* __restrict__ w1, const float* __restrict__ w2,
    bf16* __restrict__ oq, bf16* __restrict__ oo,
    bf16* __restrict__ o1, bf16* __restrict__ o2,
    const float* __restrict__ cls_embs, const float* __restrict__ gamma_g,
    const float* __restrict__ beta_g, const float* __restrict__ Wg,
    float* __restrict__ g, bf16* __restrict__ gnb)
{
  __shared__ __align__(16) float cn[DD];
  __shared__ float red[256];
  __shared__ float gsh[CC];
  __shared__ float nrm[NHEAD];
  int bid = blockIdx.x;
  int tid = threadIdx.x;
  if (bid < 1536){
    int i = bid * 256 + tid;
    int e = i * 4;
    const float* src; bf16* dst; int off;
    if (e < 786432){ src = wqkv; dst = oq; off = e; }
    else if (e < 1048576){ src = wo; dst = oo; off = e - 786432; }
    else if (e < 1310720){ src = w1; dst = o1; off = e - 1048576; }
    else { src = w2; dst = o2; off = e - 1310720; }
    float4 v = *reinterpret_cast<const float4*>(src + off);
    short4v pk;
    pk[0] = bfbits(v.x); pk[1] = bfbits(v.y); pk[2] = bfbits(v.z); pk[3] = bfbits(v.w);
    *(short4v*)&dst[off] = pk;
    return;
  }
  {
    int n = bid - 1536;
    const float* e = cls_embs + (size_t)n * DD;
    float s = 0.f, ss = 0.f;
    for (int i = tid; i < DD; i += 256){ float v = e[i]; s += v; ss += v * v; }
    red[tid] = s; __syncthreads();
    for (int st = 128; st > 0; st >>= 1){ if (tid < st) red[tid] += red[tid + st]; __syncthreads(); }
    float mean = red[0] / DD; __syncthreads();
    red[tid] = ss; __syncthreads();
    for (int st = 128; st > 0; st >>= 1){ if (tid < st) red[tid] += red[tid + st]; __syncthreads(); }
    float var = red[0] / DD - mean * mean;
    float rstd = rsqrtf(var + EPSV);
    __syncthreads();
    for (int i = tid; i < DD; i += 256) cn[i] = (e[i] - mean) * rstd * gamma_g[i] + beta_g[i];
    __syncthreads();
    for (int c = tid; c < CC; c += 256){
      const float* w = Wg + (size_t)c * DD;
      float a = 0.f;
      #pragma unroll 8
      for (int d = 0; d < DD; d++) a += cn[d] * w[d];
      gsh[c] = a;
    }
    __syncthreads();
    if (tid < NHEAD){
      float a = 0.f;
      for (int d = 0; d < HDIM; d++){ float v = gsh[tid * HDIM + d]; a += v * v; }
      nrm[tid] = fmaxf(sqrtf(a), 1e-12f);
    }
    __syncthreads();
    for (int c = tid; c < CC; c += 256){
      g[(size_t)n * CC + c] = gsh[c];
      gnb[(size_t)n * CC + c] = f2bf(gsh[c] / nrm[c >> 6]);
    }
  }
}

// ---------------- fused LN (single-pass): stage bf16 tile in LDS, stats, apply+transpose ----------------
__global__ __launch_bounds__(256, 2) void fuse_ln_k(const float* __restrict__ X,
    const float* __restrict__ lng, const float* __restrict__ lnb,
    bf16* __restrict__ xnT){
  __shared__ bf16 st[512][68];
  __shared__ float sred[2][4][64];
  __shared__ float muS[64], rsS[64];
  int p0 = blockIdx.x * 64;
  int b = p0 / LL, l0 = p0 - b * LL;
  int tid = threadIdx.x;
  #pragma unroll 4
  for (int i = 0; i < 32; i++){
    int idx = i * 256 + tid;
    int c = idx >> 4, l4 = (idx & 15) * 4;
    float4 v = *reinterpret_cast<const float4*>(X + (size_t)b * CC * LL + (size_t)c * LL + l0 + l4);
    short4v pk;
    pk[0] = bfbits(v.x); pk[1] = bfbits(v.y); pk[2] = bfbits(v.z); pk[3] = bfbits(v.w);
    *(short4v*)&st[c][l4] = pk;
  }
  __syncthreads();
  {
    int cg = tid >> 6, l = tid & 63;
    float s = 0.f, ss = 0.f;
    for (int c = cg * 128; c < cg * 128 + 128; c++){
      float v = bf2f(st[c][l]);
      s += v; ss += v * v;
    }
    sred[0][cg][l] = s; sred[1][cg][l] = ss;
  }
  __syncthreads();
  if (tid < 64){
    float st2 = sred[0][0][tid] + sred[0][1][tid] + sred[0][2][tid] + sred[0][3][tid];
    float sst = sred[1][0][tid] + sred[1][1][tid] + sred[1][2][tid] + sred[1][3][tid];
    float m = st2 * (1.0f / CC);
    float var = sst * (1.0f / CC) - m * m;
    muS[tid] = m; rsS[tid] = rsqrtf(var + EPSV);
  }
  __syncthreads();
  int pr = tid >> 4;
  int cc = (tid & 15) * 4;
  for (int cb = 0; cb < 8; cb++){
    int c0 = cb * 64;
    #pragma unroll
    for (int i = 0; i < 4; i++){
      int pl = pr + i * 16;
      int p = p0 + pl;
      float m = muS[pl], r = rsS[pl];
      short4v pk;
      #pragma unroll
      for (int e = 0; e < 4; e++){
        int c = c0 + cc + e;
        pk[e] = bfbits((bf2f(st[c][pl]) - m) * r * lng[c] + lnb[c]);
      }
      *(short4v*)&xnT[(size_t)p * CC + c0 + cc] = pk;
    }
  }
}

// ---------------- bf16 MFMA GEMM (reg-staged, XOR-swizzled LDS) ----------------
// MODE 0 (1D grid 3464): q -> qT pixel-major + rq + qssp + FUSED gm1 (gnb@q from T, pmin/pmax) ;
//                        k [b][c][l] + kssp + segp ; v -> vT ; blocks>=3456: clsobj
// MODE 1: xT = bf16(img + C + bo) + LN stat partials (statp write)
// MODE 2: h = gelu(C+b1), B = xT with inline LN (stats derived from statp)
// MODE 3: d_out = xT + C + b2
// gm1 partials use TRANSPOSED layout [bh][GMBLK][128 n] (64B-contiguous wave writes).
template<int MODE>
__global__ __launch_bounds__(256, 2) void mgemm_k(
    const bf16* __restrict__ A,
    const bf16* __restrict__ B,
    const float* __restrict__ residf,
    const bf16* __restrict__ residb,
    const float* __restrict__ bias,
    const float* __restrict__ lng, const float* __restrict__ lnb,
    float2* __restrict__ statp,
    float* __restrict__ qssp, float* __restrict__ kssp,
    bf16* __restrict__ qTo, float* __restrict__ rqo,
    bf16* __restrict__ ko, bf16* __restrict__ vo,
    bf16* __restrict__ xT_out,
    float* __restrict__ xo,
    bf16* __restrict__ ho,
    const float* __restrict__ gA, const float* __restrict__ clsl, float* __restrict__ clsovO,
    const float* __restrict__ segf, float* __restrict__ segpO,
    const bf16* __restrict__ gnbA, float* __restrict__ pminO, float* __restrict__ pmaxO)
{
  __shared__ __align__(16) short smem[128 * TP];
  __shared__ float sredf[512];
  short* Asm = smem;
  short* Bsm = smem + 8192;
  short* T   = smem;
  int tid = threadIdx.x;
  if (MODE == 0 && blockIdx.x >= 3456){
    int idx = (blockIdx.x - 3456) * 256 + tid;
    int b = idx >> 9, c = idx & 511;
    float a = 0.f;
    for (int n = 0; n < NCLS; n++) a += gA[(size_t)n * CC + c] * clsl[b * NCLS + n];
    clsovO[idx] = a;
    return;
  }
  int lane = tid & 63, wv = tid >> 6;
  int wr = wv >> 1, wc = wv & 1;
  int r15 = lane & 15, g = lane >> 4, h7 = lane & 7;
  int flat, gx, cpx;
  if (MODE == 0){ flat = blockIdx.x; gx = 12; cpx = 432; }
  else { gx = gridDim.x; flat = blockIdx.y * gx + blockIdx.x; cpx = (gx * gridDim.y) >> 3; }
  int swz = (flat & 7) * cpx + (flat >> 3);
  int m0 = (swz % gx) * 128, n0 = (swz / gx) * 128;
  int srow = tid >> 3, skkg = tid & 7;
  int sslot = ((skkg ^ (srow & 7))) * 8;

  f32x4 acc[4][4];
  #pragma unroll
  for (int i = 0; i < 4; i++)
    #pragma unroll
    for (int j = 0; j < 4; j++) acc[i][j] = (f32x4){0.f, 0.f, 0.f, 0.f};

  if (MODE == 2){
    if (tid < 128){
      int p = n0 + tid;
      float s = 0.f, ss2 = 0.f;
      #pragma unroll
      for (int part = 0; part < 4; part++){
        float2 v = statp[part * BLPIX + p];
        s += v.x; ss2 += v.y;
      }
      float m = s * (1.0f / CC);
      float var = ss2 * (1.0f / CC) - m * m;
      sredf[tid] = m;
      sredf[128 + tid] = rsqrtf(var + EPSV);
    }
    __syncthreads();
  }

  short8v pa[4], pb[4];
  auto loadAB = [&](int it){
    int k0 = it * 64;
    if (MODE == 2){
      int c0 = k0 + skkg * 8;
      float ga[8], be[8];
      *(float4*)&ga[0] = *(const float4*)&lng[c0];
      *(float4*)&ga[4] = *(const float4*)&lng[c0 + 4];
      *(float4*)&be[0] = *(const float4*)&lnb[c0];
      *(float4*)&be[4] = *(const float4*)&lnb[c0 + 4];
      #pragma unroll
      for (int r = 0; r < 4; r++){
        pa[r] = *reinterpret_cast<const short8v*>(A + (size_t)(m0 + r * 32 + srow) * 512 + c0);
        int rl = r * 32 + srow;
        float mm = sredf[rl], rr = sredf[128 + rl];
        short8v rawv = *reinterpret_cast<const short8v*>(B + (size_t)(n0 + rl) * 512 + c0);
        short8v ov;
        #pragma unroll
        for (int e = 0; e < 8; e++){
          float v = (s2f(rawv[e]) - mm) * rr * ga[e] + be[e];
          ov[e] = bfbits(v);
        }
        pb[r] = ov;
      }
    } else {
      #pragma unroll
      for (int r = 0; r < 4; r++){
        pa[r] = *reinterpret_cast<const short8v*>(A + (size_t)(m0 + r * 32 + srow) * 512 + k0 + skkg * 8);
        pb[r] = *reinterpret_cast<const short8v*>(B + (size_t)(n0 + r * 32 + srow) * 512 + k0 + skkg * 8);
      }
    }
  };

  loadAB(0);
  for (int it = 0; it < 8; ++it){
    __syncthreads();
    #pragma unroll
    for (int r = 0; r < 4; r++){
      int row = r * 32 + srow;
      *(short8v*)&Asm[row * 64 + sslot] = pa[r];
      *(short8v*)&Bsm[row * 64 + sslot] = pb[r];
    }
    __syncthreads();
    if (it < 7) loadAB(it + 1);
    #pragma unroll
    for (int s = 0; s < 2; s++){
      int slot = ((s * 4 + g) ^ h7) * 8;
      short8v af[4], bf_[4];
      #pragma unroll
      for (int i = 0; i < 4; i++){
        af[i]  = *(const short8v*)&Asm[(wr * 64 + i * 16 + r15) * 64 + slot];
        bf_[i] = *(const short8v*)&Bsm[(wc * 64 + i * 16 + r15) * 64 + slot];
      }
      #pragma unroll
      for (int i = 0; i < 4; i++)
        #pragma unroll
        for (int j = 0; j < 4; j++){
          if (MODE == 2)
            acc[i][j] = __builtin_amdgcn_mfma_f32_16x16x32_bf16(bf_[i], af[j], acc[i][j], 0, 0, 0);
          else
            acc[i][j] = __builtin_amdgcn_mfma_f32_16x16x32_bf16(af[i], bf_[j], acc[i][j], 0, 0, 0);
        }
    }
  }

  int bIdx = n0 / LL;
  int lbase = n0 - bIdx * LL;
  if (MODE == 0){
    int part = m0 >> 9;
    if (part == 0){
      int chb = m0 + wr * 64;
      int head = chb >> 6;
      int bh = bIdx * 8 + head;
      #pragma unroll
      for (int j = 0; j < 4; j++){
        float ssl = 0.f;
        #pragma unroll
        for (int i = 0; i < 4; i++)
          #pragma unroll
          for (int e = 0; e < 4; e++) ssl += acc[i][j][e] * acc[i][j][e];
        ssl += __shfl_xor(ssl, 16); ssl += __shfl_xor(ssl, 32);
        float rqv_ = 1.0f / fmaxf(sqrtf(ssl), 1e-12f);
        if (g == 0){
          int l = lbase + wc * 64 + j * 16 + r15;
          rqo[(size_t)bh * LL + l] = rqv_;
          sredf[256 + wr * 128 + wc * 64 + j * 16 + r15] = rqv_;
        }
      }
      #pragma unroll
      for (int i = 0; i < 4; i++)
        #pragma unroll
        for (int e = 0; e < 4; e++){
          float ssv = acc[i][0][e]*acc[i][0][e] + acc[i][1][e]*acc[i][1][e]
                    + acc[i][2][e]*acc[i][2][e] + acc[i][3][e]*acc[i][3][e];
          #pragma unroll
          for (int msk = 1; msk < 16; msk <<= 1) ssv += __shfl_xor(ssv, msk);
          if (r15 == 0) sredf[wv * 64 + i * 16 + g * 4 + e] = ssv;
        }
      __syncthreads();
      if (tid < 128){
        int wrr = tid >> 6, chL = tid & 63;
        float tot = sredf[(wrr * 2) * 64 + chL] + sredf[(wrr * 2 + 1) * 64 + chL];
        int c = m0 + wrr * 64 + chL;
        int row = bIdx * 512 + c;
        int ltile = lbase >> 7;
        qssp[(size_t)row * NLT + ltile] = tot;
      }
      #pragma unroll
      for (int i = 0; i < 4; i++)
        #pragma unroll
        for (int j = 0; j < 4; j++){
          int pxl = wc * 64 + j * 16 + r15;
          int chl = wr * 64 + i * 16 + g * 4;
          short4v pk;
          #pragma unroll
          for (int e = 0; e < 4; e++) pk[e] = bfbits(acc[i][j][e]);
          *(short4v*)&T[pxl * TP + chl] = pk;
        }
      __syncthreads();
      #pragma unroll
      for (int it2 = 0; it2 < 16; it2++){
        int c2 = tid + it2 * 256;
        int px = c2 >> 5, ch4 = (c2 & 31) * 4;
        *(short4v*)&qTo[((size_t)bIdx * LL + lbase + px) * CC + m0 + ch4] = *(short4v*)&T[px * TP + ch4];
      }
      // ---- fused gm1: gnb[128n x 64d] @ q (B-frags straight from T) -> pmin/pmax partials
      //      transposed layout [bh][GMBLK][128 n]: wave writes are 64B-contiguous ----
      {
        int h0 = m0 >> 6;          // 0,2,4,6 : first of the 2 heads in this ch-tile
        int ltb = lbase >> 6;      // base 64-px tile index (even)
        #pragma unroll
        for (int hh = 0; hh < 2; hh++){
          int bh2 = bIdx * 8 + h0 + hh;
          short8v ag2[2][2];
          #pragma unroll
          for (int i = 0; i < 2; i++)
            #pragma unroll
            for (int kt = 0; kt < 2; kt++)
              ag2[i][kt] = *reinterpret_cast<const short8v*>(gnbA + (size_t)(wv * 32 + i * 16 + r15) * CC + (h0 + hh) * 64 + kt * 32 + g * 8);
          #pragma unroll
          for (int ph = 0; ph < 2; ph++){
            short8v bq2[4][2];
            float rqv2[4];
            #pragma unroll
            for (int j = 0; j < 4; j++){
              #pragma unroll
              for (int kt = 0; kt < 2; kt++)
                bq2[j][kt] = *reinterpret_cast<const short8v*>(&T[(ph * 64 + j * 16 + r15) * TP + hh * 64 + kt * 32 + g * 8]);
              rqv2[j] = sredf[256 + hh * 128 + ph * 64 + j * 16 + r15];
            }
            f32x4 acc2[2][4];
            #pragma unroll
            for (int i = 0; i < 2; i++)
              #pragma unroll
              for (int j = 0; j < 4; j++) acc2[i][j] = (f32x4){0.f,0.f,0.f,0.f};
            #pragma unroll
            for (int kt = 0; kt < 2; kt++)
              #pragma unroll
              for (int i = 0; i < 2; i++)
                #pragma unroll
                for (int j = 0; j < 4; j++)
                  acc2[i][j] = __builtin_amdgcn_mfma_f32_16x16x32_bf16(ag2[i][kt], bq2[j][kt], acc2[i][j], 0, 0, 0);
            size_t pbase = ((size_t)bh2 * GMBLK + ltb + ph) * 128;
            #pragma unroll
            for (int i = 0; i < 2; i++)
              #pragma unroll
              for (int e = 0; e < 4; e++){
                float mn = 1e30f, mx = -1e30f;
                #pragma unroll
                for (int j = 0; j < 4; j++){
                  float v = acc2[i][j][e] * rqv2[j];
                  mn = fminf(mn, v); mx = fmaxf(mx, v);
                }
                #pragma unroll
                for (int msk = 1; msk < 16; msk <<= 1){
                  mn = fminf(mn, __shfl_xor(mn, msk));
                  mx = fmaxf(mx, __shfl_xor(mx, msk));
                }
                if (r15 == 0){
                  int n = wv * 32 + i * 16 + g * 4 + e;
                  pminO[pbase + n] = mn;
                  pmaxO[pbase + n] = mx;
                }
              }
          }
        }
      }
    } else if (part == 1){
      int chb = (m0 & 511) + wr * 64;
      #pragma unroll
      for (int i = 0; i < 4; i++)
        #pragma unroll
        for (int j = 0; j < 4; j++){
          int l = lbase + wc * 64 + j * 16 + r15;
          #pragma unroll
          for (int e = 0; e < 4; e++){
            int ch = chb + i * 16 + g * 4 + e;
            ko[(size_t)bIdx * CC * LL + (size_t)ch * LL + l] = f2bf(acc[i][j][e]);
          }
        }
      // sigmoid(seg) weights for this thread's 4 l's (fp32 acc = pre-rounded k)
      float sg[4];
      #pragma unroll
      for (int j = 0; j < 4; j++){
        int l = lbase + wc * 64 + j * 16 + r15;
        sg[j] = 1.0f / (1.0f + expf(-segf[(size_t)bIdx * LL + l]));
      }
      #pragma unroll
      for (int i = 0; i < 4; i++)
        #pragma unroll
        for (int e = 0; e < 4; e++){
          float ssv = acc[i][0][e]*acc[i][0][e] + acc[i][1][e]*acc[i][1][e]
                    + acc[i][2][e]*acc[i][2][e] + acc[i][3][e]*acc[i][3][e];
          float sgv = sg[0]*acc[i][0][e] + sg[1]*acc[i][1][e]
                    + sg[2]*acc[i][2][e] + sg[3]*acc[i][3][e];
          #pragma unroll
          for (int msk = 1; msk < 16; msk <<= 1){
            ssv += __shfl_xor(ssv, msk);
            sgv += __shfl_xor(sgv, msk);
          }
          if (r15 == 0){
            sredf[wv * 64 + i * 16 + g * 4 + e] = ssv;
            sredf[256 + wv * 64 + i * 16 + g * 4 + e] = sgv;
          }
        }
      __syncthreads();
      if (tid < 128){
        int wrr = tid >> 6, chL = tid & 63;
        float tot  = sredf[(wrr * 2) * 64 + chL] + sredf[(wrr * 2 + 1) * 64 + chL];
        float tots = sredf[256 + (wrr * 2) * 64 + chL] + sredf[256 + (wrr * 2 + 1) * 64 + chL];
        int c = (m0 & 511) + wrr * 64 + chL;
        int row = bIdx * 512 + c;
        int ltile = lbase >> 7;
        kssp[(size_t)row * NLT + ltile] = tot;
        segpO[(size_t)row * NLT + ltile] = tots;
      }
    } else {
      __syncthreads();
      #pragma unroll
      for (int i = 0; i < 4; i++)
        #pragma unroll
        for (int j = 0; j < 4; j++){
          int pxl = wc * 64 + j * 16 + r15;
          int chl = wr * 64 + i * 16 + g * 4;
          short4v pk;
          #pragma unroll
          for (int e = 0; e < 4; e++) pk[e] = bfbits(acc[i][j][e]);
          *(short4v*)&T[pxl * TP + chl] = pk;
        }
      __syncthreads();
      int chg = (m0 & 511);
      #pragma unroll
      for (int it2 = 0; it2 < 16; it2++){
        int c2 = tid + it2 * 256;
        int px = c2 >> 5, ch4 = (c2 & 31) * 4;
        *(short4v*)&vo[((size_t)bIdx * LL + lbase + px) * CC + chg + ch4] = *(short4v*)&T[px * TP + ch4];
      }
    }
  } else if (MODE == 1){
    __syncthreads();
    float sj[4] = {0.f,0.f,0.f,0.f}, ssj[4] = {0.f,0.f,0.f,0.f};
    #pragma unroll
    for (int i = 0; i < 4; i++)
      #pragma unroll
      for (int j = 0; j < 4; j++){
        int l = lbase + wc * 64 + j * 16 + r15;
        int chm = m0 + wr * 64 + i * 16 + g * 4;
        int pxl = wc * 64 + j * 16 + r15;
        int chl = wr * 64 + i * 16 + g * 4;
        short4v pk;
        #pragma unroll
        for (int e = 0; e < 4; e++){
          int m = chm + e;
          size_t o = (size_t)bIdx * CC * LL + (size_t)m * LL + l;
          float xv = residf[o] + acc[i][j][e] + bias[m];
          pk[e] = bfbits(xv);
          sj[j] += xv; ssj[j] += xv * xv;
        }
        *(short4v*)&T[pxl * TP + chl] = pk;
      }
    #pragma unroll
    for (int j = 0; j < 4; j++){
      sj[j] += __shfl_xor(sj[j], 16); sj[j] += __shfl_xor(sj[j], 32);
      ssj[j] += __shfl_xor(ssj[j], 16); ssj[j] += __shfl_xor(ssj[j], 32);
    }
    if (g == 0){
      #pragma unroll
      for (int j = 0; j < 4; j++){
        sredf[wv * 128 + j * 32 + r15 * 2 + 0] = sj[j];
        sredf[wv * 128 + j * 32 + r15 * 2 + 1] = ssj[j];
      }
    }
    __syncthreads();
    if (tid < 128){
      int wv2 = tid >> 6, lane2 = tid & 63, j2 = lane2 >> 4, r2 = lane2 & 15;
      float s   = sredf[wv2 * 128 + j2 * 32 + r2 * 2 + 0] + sredf[(wv2 + 2) * 128 + j2 * 32 + r2 * 2 + 0];
      float ss2 = sredf[wv2 * 128 + j2 * 32 + r2 * 2 + 1] + sredf[(wv2 + 2) * 128 + j2 * 32 + r2 * 2 + 1];
      int p = n0 + wv2 * 64 + j2 * 16 + r2;
      statp[(m0 >> 7) * BLPIX + p] = make_float2(s, ss2);
    }
    #pragma unroll
    for (int it2 = 0; it2 < 16; it2++){
      int c2 = tid + it2 * 256;
      int px = c2 >> 5, ch4 = (c2 & 31) * 4;
      *(short4v*)&xT_out[((size_t)bIdx * LL + lbase + px) * CC + m0 + ch4] = *(short4v*)&T[px * TP + ch4];
    }
  } else if (MODE == 3){
    __syncthreads();
    #pragma unroll
    for (int it2 = 0; it2 < 16; it2++){
      int c2 = tid + it2 * 256;
      int px = c2 >> 5, ch4 = (c2 & 31) * 4;
      *(short4v*)&T[px * TP + ch4] = *(const short4v*)&residb[((size_t)bIdx * LL + lbase + px) * CC + m0 + ch4];
    }
    __syncthreads();
    #pragma unroll
    for (int i = 0; i < 4; i++)
      #pragma unroll
      for (int j = 0; j < 4; j++){
        int l = lbase + wc * 64 + j * 16 + r15;
        int chm = m0 + wr * 64 + i * 16 + g * 4;
        int pxl = wc * 64 + j * 16 + r15;
        int chl = wr * 64 + i * 16 + g * 4;
        short4v rv = *(short4v*)&T[pxl * TP + chl];
        #pragma unroll
        for (int e = 0; e < 4; e++){
          int m = chm + e;
          size_t o = (size_t)bIdx * CC * LL + (size_t)m * LL + l;
          xo[o] = s2f(rv[e]) + acc[i][j][e] + bias[m];
        }
      }
  } else {
    #pragma unroll
    for (int i = 0; i < 4; i++)
      #pragma unroll
      for (int j = 0; j < 4; j++){
        int mm = m0 + wr * 64 + j * 16 + r15;
        float bv = bias[mm];
        #pragma unroll
        for (int e = 0; e < 4; e++){
          int n = n0 + wc * 64 + i * 16 + g * 4 + e;
          float t = acc[i][j][e] + bv;
          float gv = 0.5f * t * (1.0f + erff(t * 0.70710678118654752f));
          ho[(size_t)n * CC + mm] = f2bf(gv);
        }
      }
  }
}

// ================= mega1: attn(qT-staged) | segden | qn/kn/segn red =================
// [0,256) attn ; [256,260) segden ; [260,1796) red (6144 rows)
__global__ __launch_bounds__(256) void mega1_k(
    const bf16* __restrict__ qT, const float* __restrict__ rq,
    const bf16* __restrict__ k, const bf16* __restrict__ gnb,
    float* __restrict__ pmin, float* __restrict__ pmax,
    float* __restrict__ part,
    const float* __restrict__ seg, float* __restrict__ seg_num, float* __restrict__ den,
    const float* __restrict__ qssp, const float* __restrict__ kssp,
    const float* __restrict__ segp,
    float* __restrict__ qn, float* __restrict__ kn)
{
  __shared__ __align__(16) bf16 qs[128 * 68];
  int bid = blockIdx.x;
  int t = threadIdx.x;
  (void)rq; (void)gnb; (void)pmin; (void)pmax;
  if (bid < 256){
    int ls = bid & 7, bh = bid >> 3;
    int b = bh >> 3, h = bh & 7;
    int w = t >> 6, lane = t & 63, r15 = lane & 15, g = lane >> 4;
    const bf16* kp = k + (size_t)b * CC * LL + (size_t)h * HDIM * LL;
    f32x4 acc4[4];
    #pragma unroll
    for (int j = 0; j < 4; j++) acc4[j] = (f32x4){0.f,0.f,0.f,0.f};
    for (int stg = 0; stg < 9; stg++){
      int lb = ls * 1152 + stg * 128;
      #pragma unroll
      for (int it = 0; it < 8; it++){
        int idx = t + it * 256;
        int row = idx >> 4, c4 = (idx & 15) * 4;
        *(short4v*)&qs[row * 68 + c4] = *(const short4v*)&qT[((size_t)(b * LL + lb + row)) * CC + h * 64 + c4];
      }
      __syncthreads();
      #pragma unroll
      for (int kstep = 0; kstep < 4; kstep++){
        int lloc = kstep * 32 + g * 8;
        short8v aq;
        #pragma unroll
        for (int jj = 0; jj < 8; jj++)
          aq[jj] = *reinterpret_cast<short*>(&qs[(lloc + jj) * 68 + w * 16 + r15]);
        int koff = lb + kstep * 32 + g * 8;
        short8v bk[4];
        #pragma unroll
        for (int j = 0; j < 4; j++) bk[j] = *reinterpret_cast<const short8v*>(kp + (size_t)(j * 16 + r15) * LL + koff);
        #pragma unroll
        for (int j = 0; j < 4; j++)
          acc4[j] = __builtin_amdgcn_mfma_f32_16x16x32_bf16(aq, bk[j], acc4[j], 0, 0, 0);
      }
      __syncthreads();
    }
    #pragma unroll
    for (int j = 0; j < 4; j++)
      #pragma unroll
      for (int e = 0; e < 4; e++){
        int d = w * 16 + g * 4 + e;
        int ee = j * 16 + r15;
        part[((size_t)(bh * LSPLIT + ls)) * 4096 + d * 64 + ee] = acc4[j][e];
      }
    return;
  }
  if (bid < 260){
    float* red = (float*)qs;
    int b = bid - 256;
    const float* sp = seg + (size_t)b * LL;
    float s = 0.f;
    for (int i = t; i < LL; i += 256) s += 1.0f / (1.0f + expf(-sp[i]));
    red[t] = s; __syncthreads();
    for (int st = 128; st > 0; st >>= 1){ if (t < st) red[t] += red[t + st]; __syncthreads(); }
    if (t == 0) den[b] = red[0];
    return;
  }
  {
    int r4 = (bid - 260) * 4 + (t >> 6);
    int lane = t & 63;
    const float* src = (r4 < 2048) ? qssp : ((r4 < 4096) ? kssp : segp);
    int r = r4 & 2047;
    float s = src[(size_t)r * NLT + lane] + ((lane < 8) ? src[(size_t)r * NLT + 64 + lane] : 0.f);
    #pragma unroll
    for (int m = 1; m < 64; m <<= 1) s += __shfl_xor(s, m);
    if (lane == 0){
      if (r4 < 2048) qn[r] = fmaxf(sqrtf(s), 1e-12f);
      else if (r4 < 4096) kn[r] = fmaxf(sqrtf(s), 1e-12f);
      else seg_num[r] = s;
    }
  }
}

// ---------------- aux (+obj inline, staged k tile) ----------------
__global__ __launch_bounds__(256) void aux_k(const bf16* __restrict__ k,
                      const float* __restrict__ clsov, const float* __restrict__ segn,
                      const float* __restrict__ segd,
                      float* __restrict__ aux,
                      float* __restrict__ pmin, float* __restrict__ pmax){
  __shared__ bf16 ks[64 * 68];
  __shared__ float os[64];
  __shared__ float sspart[4][64], dotpart[4][64];
  int bh = blockIdx.x, lt = blockIdx.y;
  int l0 = lt * 64;
  int t = threadIdx.x;
  int b = bh >> 3, h = bh & 7;
  const bf16* kp = k + (size_t)b * CC * LL + (size_t)h * HDIM * LL + l0;
  #pragma unroll
  for (int i2 = 0; i2 < 4; i2++){
    int idx = t + i2 * 256;
    int d = idx >> 4, lch = (idx & 15) * 4;
    *(short4v*)&ks[d * 68 + lch] = *reinterpret_cast<const short4v*>(kp + (size_t)d * LL + lch);
  }
  if (t < 64){
    float sv = clsov[bh * 64 + t] + segn[bh * 64 + t] / segd[b];
    float ss2 = sv * sv;
    #pragma unroll
    for (int m = 1; m < 64; m <<= 1) ss2 += __shfl_xor(ss2, m);
    os[t] = sv / fmaxf(sqrtf(ss2), 1e-12f);
  }
  __syncthreads();
  {
    int dg = t >> 6, l = t & 63;
    float ssk = 0.f, dk = 0.f;
    #pragma unroll
    for (int dd = 0; dd < 16; dd++){
      float v = bf2f(ks[(dg * 16 + dd) * 68 + l]);
      ssk += v * v; dk += os[dg * 16 + dd] * v;
    }
    sspart[dg][l] = ssk; dotpart[dg][l] = dk;
  }
  __syncthreads();
  if (t < 64){
    float ss = sspart[0][t] + sspart[1][t] + sspart[2][t] + sspart[3][t];
    float dot = dotpart[0][t] + dotpart[1][t] + dotpart[2][t] + dotpart[3][t];
    float av = dot / fmaxf(sqrtf(ss), 1e-12f);
    aux[(size_t)bh * LL + l0 + t] = av;
    float mn = av, mx = av;
    #pragma unroll
    for (int m = 1; m < 64; m <<= 1){
      mn = fminf(mn, __shfl_xor(mn, m));
      mx = fmaxf(mx, __shfl_xor(mx, m));
    }
    if (t == 0){ pmin[bh * AUXBLK + lt] = mn; pmax[bh * AUXBLK + lt] = mx; }
  }
}

// ================= megared: gmred(transposed partials) | auxred | smax =================
__global__ __launch_bounds__(256) void megared_k(
    const float* __restrict__ gpmin, const float* __restrict__ gpmax,
    float* __restrict__ gmin, float* __restrict__ gms,
    const float* __restrict__ apmin, const float* __restrict__ apmax,
    float* __restrict__ amin, float* __restrict__ ams,
    const float* __restrict__ part, const float* __restrict__ qn,
    const float* __restrict__ kn, const float* __restrict__ scale,
    bf16* __restrict__ Pb)
{
  __shared__ float As[64 * 65];
  int bid = blockIdx.x;
  int tid = threadIdx.x;
  if (bid < 1024){
    int row = bid * 4 + (tid >> 6);
    int lane = tid & 63;
    int bh = row >> 7, n = row & 127;
    const float* pb_ = gpmin + (size_t)bh * GMBLK * 128 + n;
    const float* px_ = gpmax + (size_t)bh * GMBLK * 128 + n;
    float mn = pb_[(size_t)lane * 128];
    float mx = px_[(size_t)lane * 128];
    mn = fminf(mn, pb_[(size_t)(64 + lane) * 128]);
    mx = fmaxf(mx, px_[(size_t)(64 + lane) * 128]);
    if (lane < 16){
      mn = fminf(mn, pb_[(size_t)(128 + lane) * 128]);
      mx = fmaxf(mx, px_[(size_t)(128 + lane) * 128]);
    }
    #pragma unroll
    for (int m = 1; m < 64; m <<= 1){
      mn = fminf(mn, __shfl_xor(mn, m));
      mx = fmaxf(mx, __shfl_xor(mx, m));
    }
    if (lane == 0){ gmin[row] = mn; gms[row] = mx - mn; }
    return;
  }
  if (bid < 1032){
    int bh = (bid - 1024) * 4 + (tid >> 6);
    int lane = tid & 63;
    float mn = apmin[bh * AUXBLK + lane];
    float mx = apmax[bh * AUXBLK + lane];
    mn = fminf(mn, apmin[bh * AUXBLK + 64 + lane]);
    mx = fmaxf(mx, apmax[bh * AUXBLK + 64 + lane]);
    if (lane < 16){
      mn = fminf(mn, apmin[bh * AUXBLK + 128 + lane]);
      mx = fmaxf(mx, apmax[bh * AUXBLK + 128 + lane]);
    }
    #pragma unroll
    for (int m = 1; m < 64; m <<= 1){
      mn = fminf(mn, __shfl_xor(mn, m));
      mx = fmaxf(mx, __shfl_xor(mx, m));
    }
    if (lane == 0){ amin[bh] = mn; ams[bh] = mx - mn; }
    return;
  }
  {
    int bh = bid - 1032;
    int h = bh & 7;
    #pragma unroll
    for (int i = 0; i < 16; i++){
      int cell = tid + i * 256;
      int d = cell >> 6, e = cell & 63;
      float s = 0.f;
      #pragma unroll
      for (int ls = 0; ls < LSPLIT; ls++) s += part[((size_t)(bh * LSPLIT + ls)) * 4096 + cell];
      As[d * 65 + e] = s * scale[h] / (qn[bh * 64 + d] * kn[bh * 64 + e]);
    }
    __syncthreads();
    if (tid < 64){
      int d = tid;
      float mx = -1e30f;
      for (int e = 0; e < 64; e++) mx = fmaxf(mx, As[d * 65 + e]);
      float sum = 0.f;
      for (int e = 0; e < 64; e++){ float ev = expf(As[d * 65 + e] - mx); As[d * 65 + e] = ev; sum += ev; }
      float inv = 1.0f / sum;
      for (int e = 0; e < 64; e++) Pb[(size_t)bh * 4096 + d * 64 + e] = f2bf(As[d * 65 + e] * inv);
    }
  }
}

// ---------------- pv (MFMA, qT-based) ----------------
__global__ __launch_bounds__(256) void pv_k(const bf16* __restrict__ qT, const float* __restrict__ rq,
      const bf16* __restrict__ gnb,
      const float* __restrict__ aux,
      const float* __restrict__ gmin, const float* __restrict__ gms,
      const float* __restrict__ amin, const float* __restrict__ ams,
      const bf16* __restrict__ Pb, const bf16* __restrict__ vT, bf16* __restrict__ outT){
  __shared__ float gminS[128], rgmsS[128];
  __shared__ float separt[4][64], setpart[4][64];
  __shared__ float wl[64];
  int bh = blockIdx.x, lt = blockIdx.y;
  int l0 = lt * 64;
  int t = threadIdx.x;
  int b = bh >> 3, h = bh & 7;
  int w = t >> 6, lane = t & 63, r15 = lane & 15, g = lane >> 4;
  if (t < 128){ gminS[t] = gmin[bh * 128 + t]; rgmsS[t] = 1.0f / gms[bh * 128 + t]; }
  short8v ag[2][2];
  #pragma unroll
  for (int i = 0; i < 2; i++)
    #pragma unroll
    for (int kt = 0; kt < 2; kt++)
      ag[i][kt] = *reinterpret_cast<const short8v*>(gnb + (size_t)(w * 32 + i * 16 + r15) * CC + h * 64 + kt * 32 + g * 8);
  const bf16* qTp = qT + ((size_t)(b * LL + l0)) * CC + h * 64;
  short8v bq[4][2];
  float rqv[4];
  #pragma unroll
  for (int j = 0; j < 4; j++){
    #pragma unroll
    for (int kt = 0; kt < 2; kt++)
      bq[j][kt] = *reinterpret_cast<const short8v*>(qTp + (size_t)(j * 16 + r15) * CC + kt * 32 + g * 8);
    rqv[j] = rq[(size_t)bh * LL + l0 + j * 16 + r15];
  }
  f32x4 acc[2][4];
  #pragma unroll
  for (int i = 0; i < 2; i++)
    #pragma unroll
    for (int j = 0; j < 4; j++) acc[i][j] = (f32x4){0.f,0.f,0.f,0.f};
  #pragma unroll
  for (int kt = 0; kt < 2; kt++)
    #pragma unroll
    for (int i = 0; i < 2; i++)
      #pragma unroll
      for (int j = 0; j < 4; j++)
        acc[i][j] = __builtin_amdgcn_mfma_f32_16x16x32_bf16(ag[i][kt], bq[j][kt], acc[i][j], 0, 0, 0);
  __syncthreads();
  float seL[4] = {0.f,0.f,0.f,0.f}, setL[4] = {0.f,0.f,0.f,0.f};
  #pragma unroll
  for (int i = 0; i < 2; i++)
    #pragma unroll
    for (int j = 0; j < 4; j++)
      #pragma unroll
      for (int e = 0; e < 4; e++){
        int n = w * 32 + i * 16 + g * 4 + e;
        float tt = (acc[i][j][e] * rqv[j] - gminS[n]) * rgmsS[n];
        float ee = __expf(tt);
        seL[j] += ee; setL[j] += ee * tt;
      }
  #pragma unroll
  for (int j = 0; j < 4; j++){
    seL[j] += __shfl_xor(seL[j], 16); seL[j] += __shfl_xor(seL[j], 32);
    setL[j] += __shfl_xor(setL[j], 16); setL[j] += __shfl_xor(setL[j], 32);
  }
  if (g == 0){
    #pragma unroll
    for (int j = 0; j < 4; j++){ separt[w][j * 16 + r15] = seL[j]; setpart[w][j * 16 + r15] = setL[j]; }
  }
  __syncthreads();
  if (t < 64){
    float se = separt[0][t] + separt[1][t] + separt[2][t] + separt[3][t];
    float st = setpart[0][t] + setpart[1][t] + setpart[2][t] + setpart[3][t];
    float gmred = st / se;
    float auxn = (aux[(size_t)bh * LL + l0 + t] - amin[bh]) / ams[bh];
    wl[t] = gmred * auxn;
  }
  __syncthreads();
  short8v ap[4][2];
  #pragma unroll
  for (int i = 0; i < 4; i++)
    #pragma unroll
    for (int kt = 0; kt < 2; kt++)
      ap[i][kt] = *reinterpret_cast<const short8v*>(Pb + (size_t)bh * 4096 + (i * 16 + r15) * 64 + kt * 32 + g * 8);
  const bf16* vrow = vT + ((size_t)b * LL + l0 + w * 16 + r15) * CC + h * 64;
  short8v bv[2];
  #pragma unroll
  for (int kt = 0; kt < 2; kt++) bv[kt] = *reinterpret_cast<const short8v*>(vrow + kt * 32 + g * 8);
  f32x4 oacc[4];
  #pragma unroll
  for (int i = 0; i < 4; i++) oacc[i] = (f32x4){0.f,0.f,0.f,0.f};
  #pragma unroll
  for (int kt = 0; kt < 2; kt++)
    #pragma unroll
    for (int i = 0; i < 4; i++)
      oacc[i] = __builtin_amdgcn_mfma_f32_16x16x32_bf16(ap[i][kt], bv[kt], oacc[i], 0, 0, 0);
  float wlv = wl[w * 16 + r15];
  bf16* orow = outT + ((size_t)b * LL + l0 + w * 16 + r15) * CC + h * 64;
  #pragma unroll
  for (int i = 0; i < 4; i++){
    short4v pk;
    #pragma unroll
    for (int e = 0; e < 4; e++) pk[e] = bfbits(oacc[i][e] * wlv);
    *(short4v*)&orow[i * 16 + g * 4] = pk;
  }
}

extern "C" void kernel_launch(void* const* d_in, const int* in_sizes, int n_in,
                              void* d_out, int out_size, void* d_ws, size_t ws_size,
                              hipStream_t stream){
  const float* img        = (const float*)d_in[0];
  const float* cls_embs   = (const float*)d_in[1];
  const float* cls_logits = (const float*)d_in[2];
  const float* seg        = (const float*)d_in[3];
  const float* gamma_g    = (const float*)d_in[4];
  const float* beta_g     = (const float*)d_in[5];
  const float* gamma_f    = (const float*)d_in[6];
  const float* beta_f     = (const float*)d_in[7];
  const float* attn_scale = (const float*)d_in[8];
  const float* Wg         = (const float*)d_in[9];
  const float* Wqkv       = (const float*)d_in[10];
  const float* Wo         = (const float*)d_in[11];
  const float* bo         = (const float*)d_in[12];
  const float* gamma_n    = (const float*)d_in[13];
  const float* beta_n     = (const float*)d_in[14];
  const float* W1         = (const float*)d_in[15];
  const float* b1         = (const float*)d_in[16];
  const float* W2         = (const float*)d_in[17];
  const float* b2         = (const float*)d_in[18];
  float* outp = (float*)d_out;
  (void)in_sizes; (void)n_in; (void)out_size;

  char* wsb = (char*)d_ws;
  size_t off = 0;
  auto alloc = [&](size_t bytes)->char*{
    char* p = wsb + off;
    off += (bytes + 255) & ~(size_t)255;
    return p;
  };
  float2* statp= (float2*)alloc((size_t)4 * BLPIX * 8);
  float* qssp  = (float*)alloc((size_t)2048 * NLT * 4);
  float* kssp  = (float*)alloc((size_t)2048 * NLT * 4);
  float* segp  = (float*)alloc((size_t)2048 * NLT * 4);
  float* qn    = (float*)alloc(2048 * 4);
  float* kn    = (float*)alloc(2048 * 4);
  float* rqb   = (float*)alloc((size_t)32 * LL * 4);
  float* gbuf  = (float*)alloc((size_t)NCLS * CC * 4);
  bf16*  gnbb  = (bf16*)alloc((size_t)NCLS * CC * 2);
  float* clsov = (float*)alloc(2048 * 4);
  float* segn  = (float*)alloc(2048 * 4);
  float* segd  = (float*)alloc(256);
  float* gminp = (float*)alloc((size_t)32 * 128 * GMBLK * 4);
  float* gmaxp = (float*)alloc((size_t)32 * 128 * GMBLK * 4);
  float* gminv = (float*)alloc(4096 * 4);
  float* gmsv  = (float*)alloc(4096 * 4);
  float* auxv  = (float*)alloc((size_t)32 * LL * 4);
  float* apmin = (float*)alloc(32 * AUXBLK * 4);
  float* apmax = (float*)alloc(32 * AUXBLK * 4);
  float* aminv = (float*)alloc(256);
  float* amsv  = (float*)alloc(256);
  bf16*  Pb    = (bf16*)alloc((size_t)32 * 4096 * 2);
  float* apart = (float*)alloc((size_t)32 * LSPLIT * 4096 * 4);
  bf16* qb    = (bf16*)alloc((size_t)BB * CC * LL * 2);   // holds qT pixel-major
  bf16* kb    = (bf16*)alloc((size_t)BB * CC * LL * 2);
  bf16* wqkvb = (bf16*)alloc((size_t)1536 * 512 * 2);
  bf16* wob   = (bf16*)alloc((size_t)512 * 512 * 2);
  bf16* w1b   = (bf16*)alloc((size_t)512 * 512 * 2);
  bf16* w2b   = (bf16*)alloc((size_t)512 * 512 * 2);
  bf16* vT  = (bf16*)d_out;                                       // [0, 37.75 MB)
  bf16* xnT = (bf16*)((char*)d_out + (size_t)BB * CC * LL * 2);   // [37.75, 75.5 MB)
  bf16* qTb = qb;
  bf16* outT = kb;   // pv output (k dead after attn/aux)
  bf16* xT   = qb;   // x bf16 (qT dead after pv)
  bf16* hbT  = kb;   // MLP hidden (outT dead after MODE1)
  if (off > ws_size) return;

  // 1. wcast | clsg
  wclsg_k<<<1664, 256, 0, stream>>>(Wqkv, Wo, W1, W2, wqkvb, wob, w1b, w2b,
      cls_embs, gamma_g, beta_g, Wg, gbuf, gnbb);
  // 2. fused LN stats+apply+transpose (single img pass)
  fuse_ln_k<<<576, 256, 0, stream>>>(img, gamma_f, beta_f, xnT);
  // 3. qkv GEMM (+qT/rq/qssp/kssp/segp/gm1 epilogues) + clsobj
  mgemm_k<0><<<3464, 256, 0, stream>>>(wqkvb, xnT, nullptr, nullptr, nullptr,
      nullptr, nullptr, nullptr, qssp, kssp,
      qTb, rqb, kb, vT, nullptr, nullptr, nullptr,
      gbuf, cls_logits, clsov, seg, segp,
      gnbb, gminp, gmaxp);
  // 4. attn | segden | qn/kn/segn reduce
  mega1_k<<<1796, 256, 0, stream>>>(qTb, rqb, kb, gnbb, gminp, gmaxp, apart,
      seg, segn, segd, qssp, kssp, segp, qn, kn);
  // 5. aux (+obj)
  aux_k<<<dim3(32, 144), 256, 0, stream>>>(kb, clsov, segn, segd, auxv, apmin, apmax);
  // 6. gmred | auxred | smax
  megared_k<<<1064, 256, 0, stream>>>(gminp, gmaxp, gminv, gmsv,
      apmin, apmax, aminv, amsv,
      apart, qn, kn, attn_scale, Pb);
  // 7. pv
  pv_k<<<dim3(32, GMBLK), 256, 0, stream>>>(qTb, rqb, gnbb, auxv, gminv, gmsv, aminv, amsv, Pb, vT, outT);
  // 8. x = img + Wo@outT + bo -> xT bf16 + LN stat partials
  mgemm_k<1><<<dim3(4, 288), 256, 0, stream>>>(wob, outT, img, nullptr, bo,
      nullptr, nullptr, statp, nullptr, nullptr,
      nullptr, nullptr, nullptr, nullptr, xT, nullptr, nullptr,
      nullptr, nullptr, nullptr, nullptr, nullptr,
      nullptr, nullptr, nullptr);
  // 9. h = gelu(W1 @ LN(xT) + b1)  (stats derived from statp inline)
  mgemm_k<2><<<dim3(4, 288), 256, 0, stream>>>(w1b, xT, nullptr, nullptr, b1,
      gamma_n, beta_n, statp, nullptr, nullptr,
      nullptr, nullptr, nullptr, nullptr, nullptr, nullptr, hbT,
      nullptr, nullptr, nullptr, nullptr, nullptr,
      nullptr, nullptr, nullptr);
  // 10. out = xT + W2 @ h + b2
  mgemm_k<3><<<dim3(4, 288), 256, 0, stream>>>(w2b, hbT, nullptr, xT, b2,
      nullptr, nullptr, nullptr, nullptr, nullptr,
      nullptr, nullptr, nullptr, nullptr, nullptr, outp, nullptr,
      nullptr, nullptr, nullptr, nullptr, nullptr,
      nullptr, nullptr, nullptr);
}